// Round 9
// baseline (113.832 us; speedup 1.0000x reference)
//
#include <hip/hip_runtime.h>
#include <stdint.h>

// AAF loss, round 21: validated R17 re-pairing algebra ported onto the
// validated R16 skeleton (32x16 tiles, 512 thr, 3 blocks/CU), with an (a,d)
// row layout that avoids all three prior failure modes:
//  - no spill: Lh[10] removed from regs (border reconstructs l = log2(a)-d),
//    paying for the +4 re-pair scalars; stage-1 math identical to R16
//    (no extra exp2 -- R19's mistake).
//  - rows: a-pairs words 0..9, d-pairs 10..19 (same 80B/16B-aligned stride);
//    TL[row] = lab<<16 | f16(T), T = sum(a*d+l) (f16 T validated in R17).
//  - deep stage-2 per neighbor: 3 vector reads + 10 fdot2 + dot = T_N - acc
//    - SL; klL/klR from 2 FIXED-offset u16 reads + 1 log2 (~30 VALU vs 78).
//    Reverse (@labN) terms arrive symmetrically from the neighbor,
//    pre-weighted by swen[nlab] (exact re-partition, absmax 0.0 x3 in R17).
//  - seams: deep blocks pure re-pair; ring-1 per-neighbor E-check with
//    self-contained fallback; border blocks self-contained incl. pads
//    (ekall loops classes 0..18, l reconstructed; no K2PAD fixup needed).
// LDS: TG dropped (label in TL); reduction scratch aliases dead patch[] ->
// 54,220 B declared -> 54,272 rounded (512B gran) <= 54,613 -> 3 blocks/CU.

#define NC 19
#define HH 512
#define WW 512
#define NB 2
#define TSY 32
#define TSX 16
#define HS 18                          // halo grid cols = TSX + 2
#define VS 34                          // halo grid rows = TSY + 2
#define HP (VS * HS)                   // 612
#define ATRS 20                        // words: a-pairs 0..9, d-pairs 10..19
#define PS 35                          // 7x5 source patch per class
#define NBLK 1024
#define LOG2E 1.4426950408889634f
#define LN2 0.6931471805599453f
#define LOG2EPS -13.287712379549449f   // log2(1e-4)
#define K2F 4.3280851226668906f        // 3/ln2: KLD margin in log2 units
#define A_PAD 1e-4f
#define T1_PAD (-0.0013287712379549449f)  // 1e-4 * LOG2EPS: per-class pad t
#define T_PAD (-0.025246653521143952f)    // 19 * T1_PAD

typedef _Float16 f16x2 __attribute__((ext_vector_type(2)));

#if __has_builtin(__builtin_amdgcn_exp2f)
#define EXP2F(x) __builtin_amdgcn_exp2f(x)
#else
#define EXP2F(x) __expf((x) * LN2)
#endif

#if __has_builtin(__builtin_amdgcn_fdot2)
#define FDOT2(a, b, c) __builtin_amdgcn_fdot2((a), (b), (c), false)
#else
#define FDOT2(a, b, c) fmaf((float)(a)[1], (float)(b)[1], fmaf((float)(a)[0], (float)(b)[0], (c)))
#endif

struct Part { float es, ns; unsigned int ec, nc; };

union U32F2 { uint32_t u; f16x2 h; };
__device__ __forceinline__ uint32_t bc_u32(f16x2 v) { U32F2 x; x.h = v; return x.u; }
__device__ __forceinline__ f16x2 bc_h2(uint32_t v) { U32F2 x; x.u = v; return x.h; }

union U16H { uint16_t u; _Float16 h; };
__device__ __forceinline__ uint32_t pack_TL(int lab, float T) {
    U16H t; t.h = (_Float16)T;
    return ((uint32_t)lab << 16) | (uint32_t)t.u;
}
__device__ __forceinline__ float TL_T(uint32_t tl) {
    U16H t; t.u = (uint16_t)(tl & 0xFFFFu);
    return (float)t.h;
}

// One pixel's softmax -> a-words 0..9 + d-words 10..19 (f16 pairs) + TL.
// All log2 domain. KEEP: d-pairs kept in regs + SL = sum(l).
// Returns label (255 = OOB pad; pad rows write TL only -- never dereferenced).
template <bool KEEP>
__device__ __forceinline__ int pix_compute(const float* __restrict__ patch,
                                           const int* __restrict__ tg,
                                           int y, int x, int y0b, int x0b,
                                           uint32_t* __restrict__ ATrow,
                                           uint32_t* __restrict__ TLw,
                                           f16x2* __restrict__ Dh,
                                           float* __restrict__ SLp) {
    const bool oob = ((unsigned)y >= (unsigned)HH) | ((unsigned)x >= (unsigned)WW);
    if (oob) {
        *TLw = pack_TL(255, T_PAD);
        if (KEEP) {
            const _Float16 dP = (_Float16)LOG2EPS;
#pragma unroll
            for (int j = 0; j < 10; ++j)
                Dh[j] = (j < 9) ? (f16x2){dP, dP} : (f16x2){dP, (_Float16)0.0f};
            *SLp = 0.0f;
        }
        return 255;
    }

    const int lab = tg[(y << 9) + x];
    const float fy = (float)(y * 63) / 511.0f;
    const float fx = (float)(x * 63) / 511.0f;
    const int y0 = (int)fy, x0 = (int)fx;
    const float wy = fy - (float)y0, wx = fx - (float)x0;
    const int y1 = min(y0 + 1, 63), x1 = min(x0 + 1, 63);
    const float omwy = 1.0f - wy, omwx = 1.0f - wx;
    const float w00 = omwy * omwx, w01 = omwy * wx;
    const float w10 = wy * omwx,   w11 = wy * wx;
    const int o00 = (y0 - y0b) * 5 + (x0 - x0b);
    const int o01 = o00 + (x1 - x0);
    const int o10 = o00 + (y1 - y0) * 5;
    const int o11 = o10 + (x1 - x0);

    // v2 = logits * log2e (patch pre-scaled); no max-subtraction needed.
    float v2[NC], w[NC];
    float s = 0.0f;
#pragma unroll
    for (int c = 0; c < NC; ++c) {
        const float* pc_ = &patch[c * PS];
        const float vv = fmaf(pc_[o00], w00, fmaf(pc_[o01], w01,
                          fmaf(pc_[o10], w10, pc_[o11] * w11)));
        v2[c] = vv;
        const float e = EXP2F(vv);
        w[c] = e;
        s += e;
    }
    const float inv = 1.0f / s;
    const float lns2 = __log2f(s);            // log2 p = v2 - lns2

    float Tdd = 0.0f, SL = 0.0f;
#pragma unroll
    for (int jp = 0; jp < 10; jp += 2) {
        uint32_t aw0 = 0u, aw1 = 0u, dw0 = 0u, dw1 = 0u;
#pragma unroll
        for (int q = 0; q < 2; ++q) {
            const int j = jp + q;
            _Float16 a0h, d0h, a1h = (_Float16)0.0f, d1h = (_Float16)0.0f;
            {
                const int c = 2 * j;
                const float p = w[c] * inv;
                const float la = fmaxf(v2[c] - lns2, LOG2EPS);
                const float aa = fmaxf(p, 1e-4f);
                const float lb = __log2f(fmaxf(1.0f - p, 1e-4f));
                a0h = (_Float16)aa;
                d0h = (_Float16)(la - lb);
                Tdd = fmaf((float)a0h, (float)d0h, Tdd);
                SL += lb;
            }
            if (2 * j + 1 < NC) {
                const int c = 2 * j + 1;
                const float p = w[c] * inv;
                const float la = fmaxf(v2[c] - lns2, LOG2EPS);
                const float aa = fmaxf(p, 1e-4f);
                const float lb = __log2f(fmaxf(1.0f - p, 1e-4f));
                a1h = (_Float16)aa;
                d1h = (_Float16)(la - lb);
                Tdd = fmaf((float)a1h, (float)d1h, Tdd);
                SL += lb;
            }
            if (q == 0) { aw0 = bc_u32((f16x2){a0h, a1h}); dw0 = bc_u32((f16x2){d0h, d1h}); }
            else        { aw1 = bc_u32((f16x2){a0h, a1h}); dw1 = bc_u32((f16x2){d0h, d1h}); }
            if (KEEP) Dh[j] = (f16x2){d0h, d1h};
        }
        uint2 av; av.x = aw0; av.y = aw1;
        uint2 dv; dv.x = dw0; dv.y = dw1;
        *reinterpret_cast<uint2*>(ATrow + jp) = av;        // ds_write_b64
        *reinterpret_cast<uint2*>(ATrow + 10 + jp) = dv;   // ds_write_b64
    }
    *TLw = pack_TL(lab, Tdd + SL);
    if (KEEP) *SLp = SL;
    return lab;
}

__global__ __launch_bounds__(512, 6) void k_fused(const float* __restrict__ preds,
                                                  const int* __restrict__ targets,
                                                  const float* __restrict__ w_edge,
                                                  const float* __restrict__ w_not_edge,
                                                  Part* __restrict__ pb) {
    __shared__ __align__(16) uint32_t AT[HP * ATRS];  // 48,960 B
    __shared__ uint32_t TL[HP];                       // 2,448 B (lab<<16 | f16 T)
    __shared__ float2 swen[NC];                       // 152 B (swe, swn) ln2-folded
    __shared__ float patch[NC * PS];                  // 2,660 B; aliased as
                                                      // reduction scratch later
    const int tid = threadIdx.x;
    const int bx = blockIdx.x, by = blockIdx.y, n = blockIdx.z;

    if (tid < NC) {
        float sw_e, sw_n;
        {
            float a = w_edge[tid * 3 + 0], b = w_edge[tid * 3 + 1], c = w_edge[tid * 3 + 2];
            float m = fmaxf(a, fmaxf(b, c));
            float ea = __expf(a - m), eb = __expf(b - m), ec = __expf(c - m);
            sw_e = (ea / (ea + eb + ec)) * LN2;       // ln2: log2-domain rescale
        }
        {
            float a = w_not_edge[tid * 3 + 0], b = w_not_edge[tid * 3 + 1], c = w_not_edge[tid * 3 + 2];
            float m = fmaxf(a, fmaxf(b, c));
            float ea = __expf(a - m), eb = __expf(b - m), ec = __expf(c - m);
            sw_n = (ea / (ea + eb + ec)) * LN2;
        }
        swen[tid] = make_float2(sw_e, sw_n);
    }

    const int* tg = targets + (n << 18);
    const float* pbase = preds + (size_t)n * NC * 4096;

    const int ty = tid >> 4, tx = tid & 15;           // ty 0..31
    const int hi = (ty + 1) * HS + (tx + 1);
    const int DOFF[8] = {-HS - 1, -HS, -HS + 1, -1, 1, HS - 1, HS, HS + 1};
    const int DY[8] = {-1, -1, -1, 0, 0, 1, 1, 1};
    const int DX[8] = {-1, 0, 1, -1, 1, -1, 0, 1};

    float e_s = 0.0f, ne_s = 0.0f;
    unsigned int cnt = 0;               // e_c << 16 | ne_c (per-thread max 16|152)

    // ---- stage 0: stage 7x5x19 source patch, pre-scaled by log2e ----
    const int yT = max(by * TSY - 1, 0), xL = max(bx * TSX - 1, 0);
    const int y0b = (yT * 63) / 511, x0b = (xL * 63) / 511;
    for (int t = tid; t < NC * PS; t += 512) {
        const int c = t / PS, r = t - c * PS;
        const int ry = r / 5, rx = r - ry * 5;
        const int sy = min(y0b + ry, 63), sx = min(x0b + rx, 63);
        patch[t] = pbase[c * 4096 + (sy << 6) + sx] * LOG2E;
    }
    __syncthreads();

    // ---- stage 1: halo ring first (temps die), then own pixel ----
    if (tid < 100) {
        int i;
        if (tid < 18)      i = tid;                       // top row (row 0)
        else if (tid < 36) i = 33 * HS + (tid - 18);      // bottom row (row 33)
        else if (tid < 68) i = (tid - 35) * HS;           // left col (rows 1..32)
        else               i = (tid - 67) * HS + 17;      // right col (rows 1..32)
        const int hy = i / HS, hx = i - hy * HS;
        pix_compute<false>(patch, tg, by * TSY + hy - 1, bx * TSX + hx - 1,
                           y0b, x0b, &AT[i * ATRS], &TL[i], nullptr, nullptr);
    }

    f16x2 Dh[10];
    float SL;
    const int lab = pix_compute<true>(patch, tg, by * TSY + ty, bx * TSX + tx,
                                      y0b, x0b, &AT[hi * ATRS], &TL[hi], Dh, &SL);
    // Own-label scalars from the just-written row (same-thread RAW; exactly
    // the f16 values neighbors use for the reverse-paired terms).
    const uint32_t* myrow = &AT[hi * ATRS];
    const _Float16* hM = reinterpret_cast<const _Float16*>(myrow);
    const float aown = (float)hM[lab];                 // a@lab (lab<=18 always
    const float dlab = (float)hM[20 + lab];            //  for in-tile pixels)
    const float llab = __log2f(aown) - dlab;           // l = log2(a) - d (exact)
    const float u = fmaf(aown, dlab, llab);            // t@lab
    __syncthreads();

    // ---- stage 2 (log2 units; margin K2F) ----
    const bool interior_blk = (bx > 0) & (bx < 31) & (by > 0) & (by < 15);
    const bool deep_blk = (bx > 1) & (bx < 30) & (by > 1) & (by < 14);
    float es_o = 0.0f, ns_o = 0.0f;     // owner-weighted (x swen[lab] at end)
    float es_w = 0.0f, ns_w = 0.0f;     // pre-weighted reverse contributions

    if (deep_blk) {
#pragma unroll
        for (int k = 0; k < 8; ++k) {
            const int np = hi + DOFF[k];
            const uint32_t tl = TL[np];
            const int nlab = (int)(tl >> 16);
            const float T_N = TL_T(tl);
            const uint32_t* rb = &AT[np * ATRS];
            const _Float16* hN = reinterpret_cast<const _Float16*>(rb);
            const uint4 A0 = *reinterpret_cast<const uint4*>(rb);
            const uint4 A1 = *reinterpret_cast<const uint4*>(rb + 4);
            const uint2 A2 = *reinterpret_cast<const uint2*>(rb + 8);
            float acc = 0.0f;
            acc = FDOT2(bc_h2(A0.x), Dh[0], acc);
            acc = FDOT2(bc_h2(A0.y), Dh[1], acc);
            acc = FDOT2(bc_h2(A0.z), Dh[2], acc);
            acc = FDOT2(bc_h2(A0.w), Dh[3], acc);
            acc = FDOT2(bc_h2(A1.x), Dh[4], acc);
            acc = FDOT2(bc_h2(A1.y), Dh[5], acc);
            acc = FDOT2(bc_h2(A1.z), Dh[6], acc);
            acc = FDOT2(bc_h2(A1.w), Dh[7], acc);
            acc = FDOT2(bc_h2(A2.x), Dh[8], acc);
            acc = FDOT2(bc_h2(A2.y), Dh[9], acc);
            const float dot = T_N - acc - SL;
            const float aN = (float)hN[lab];           // fixed own-label offset
            const float dN = (float)hN[20 + lab];
            const float lN = __log2f(aN) - dN;
            const float klL = fmaf(aN, dN - dlab, lN - llab);  // kl(P,N)@labP
            const float klR = u - fmaf(aown, dN, lN);          // kl(N,P)@labP
            const bool df = (lab != nlab);
            const float wg = df ? 1.0f : 0.0f;
            const float2 sw = swen[nlab];
            es_o = fmaf(wg, fmaxf(K2F - klL, 0.0f), es_o);
            ns_o += dot - wg * klL;
            es_w = fmaf(wg * sw.x, fmaxf(K2F - klR, 0.0f), es_w);
            ns_w = fmaf(-wg * sw.y, klR, ns_w);
            cnt += df ? ((2u << 16) | (NC - 2)) : NC;
        }
    } else if (interior_blk) {
        const int gy = by * TSY + ty, gx = bx * TSX + tx;
#pragma unroll
        for (int k = 0; k < 8; ++k) {
            const int np = hi + DOFF[k];
            const uint32_t tl = TL[np];
            const int nlab = (int)(tl >> 16);
            const float T_N = TL_T(tl);
            const uint32_t* rb = &AT[np * ATRS];
            const _Float16* hN = reinterpret_cast<const _Float16*>(rb);
            const uint4 A0 = *reinterpret_cast<const uint4*>(rb);
            const uint4 A1 = *reinterpret_cast<const uint4*>(rb + 4);
            const uint2 A2 = *reinterpret_cast<const uint2*>(rb + 8);
            float acc = 0.0f;
            acc = FDOT2(bc_h2(A0.x), Dh[0], acc);
            acc = FDOT2(bc_h2(A0.y), Dh[1], acc);
            acc = FDOT2(bc_h2(A0.z), Dh[2], acc);
            acc = FDOT2(bc_h2(A0.w), Dh[3], acc);
            acc = FDOT2(bc_h2(A1.x), Dh[4], acc);
            acc = FDOT2(bc_h2(A1.y), Dh[5], acc);
            acc = FDOT2(bc_h2(A1.z), Dh[6], acc);
            acc = FDOT2(bc_h2(A1.w), Dh[7], acc);
            acc = FDOT2(bc_h2(A2.x), Dh[8], acc);
            acc = FDOT2(bc_h2(A2.y), Dh[9], acc);
            const float dot = T_N - acc - SL;
            const float aN = (float)hN[lab];
            const float dN = (float)hN[20 + lab];
            const float lN = __log2f(aN) - dN;
            const float klL = fmaf(aN, dN - dlab, lN - llab);
            const bool df = (lab != nlab);
            const float wg = df ? 1.0f : 0.0f;
            const int gyN = gy + DY[k], gxN = gx + DX[k];
            // E: neighbor pixel lies inside the interior-block region
            const bool E = ((unsigned)(gyN - TSY) < (HH - 2 * TSY)) &
                           ((unsigned)(gxN - TSX) < (WW - 2 * TSX));
            if (E) {
                const float klR = u - fmaf(aown, dN, lN);
                const float2 sw = swen[nlab];
                es_o = fmaf(wg, fmaxf(K2F - klL, 0.0f), es_o);
                ns_o += dot - wg * klL;
                es_w = fmaf(wg * sw.x, fmaxf(K2F - klR, 0.0f), es_w);
                ns_w = fmaf(-wg * sw.y, klR, ns_w);
            } else {
                // self-contained: neighbor in border block (in-image, no pad)
                const float aN2 = (float)hN[nlab];
                const float dN2 = (float)hN[20 + nlab];
                const float lN2 = __log2f(aN2) - dN2;
                const float aOo = (float)hM[nlab];
                const float dOo = (float)hM[20 + nlab];
                const float lOo = __log2f(aOo) - dOo;
                const float klN = fmaf(aN2, dN2 - dOo, lN2 - lOo);
                es_o = fmaf(wg, fmaxf(K2F - klL, 0.0f) + fmaxf(K2F - klN, 0.0f), es_o);
                ns_o += dot - wg * (klL + klN);
            }
            cnt += df ? ((2u << 16) | (NC - 2)) : NC;
        }
    } else if (lab <= NC - 1) {
        // ---- border path: self-contained, pads + reverse-ignore gates ----
#pragma unroll
        for (int k = 0; k < 8; ++k) {
            const int off = DOFF[k];
            const int rlab = (int)(TL[hi - off] >> 16);
            const bool rvalid = (rlab <= NC - 1);
            const int np = hi + off;
            const uint32_t tl = TL[np];
            const int nlab = (int)(tl >> 16);
            const bool isPad = (nlab == 255);
            float ek_k, nk_k;
            unsigned int pc;
            if (isPad) {
                // kl(P,pad)_c = T1_PAD - A_PAD*d_c - l_c; l_c = log2(a_c)-d_c.
                // Classes 0..18 only (slot 19 excluded -> no K2PAD fixup).
                float ekall = 0.0f;
#pragma unroll
                for (int j = 0; j < 10; ++j) {
                    const f16x2 ap = bc_h2(myrow[j]);
                    const float a0 = (float)ap[0], d0 = (float)Dh[j][0];
                    const float l0 = __log2f(a0) - d0;
                    const float kl0 = T1_PAD - fmaf(A_PAD, d0, l0);
                    ekall += fmaxf(K2F - kl0, 0.0f);
                    if (2 * j + 1 < NC) {
                        const float a1 = (float)ap[1], d1 = (float)Dh[j][1];
                        const float l1 = __log2f(a1) - d1;
                        const float kl1 = T1_PAD - fmaf(A_PAD, d1, l1);
                        ekall += fmaxf(K2F - kl1, 0.0f);
                    }
                }
                ek_k = ekall;
                nk_k = 0.0f;
                pc = NC;
            } else {
                const float T_N = TL_T(tl);
                const uint32_t* rb = &AT[np * ATRS];
                const _Float16* hN = reinterpret_cast<const _Float16*>(rb);
                const uint4 A0 = *reinterpret_cast<const uint4*>(rb);
                const uint4 A1 = *reinterpret_cast<const uint4*>(rb + 4);
                const uint2 A2 = *reinterpret_cast<const uint2*>(rb + 8);
                float acc = 0.0f;
                acc = FDOT2(bc_h2(A0.x), Dh[0], acc);
                acc = FDOT2(bc_h2(A0.y), Dh[1], acc);
                acc = FDOT2(bc_h2(A0.z), Dh[2], acc);
                acc = FDOT2(bc_h2(A0.w), Dh[3], acc);
                acc = FDOT2(bc_h2(A1.x), Dh[4], acc);
                acc = FDOT2(bc_h2(A1.y), Dh[5], acc);
                acc = FDOT2(bc_h2(A1.z), Dh[6], acc);
                acc = FDOT2(bc_h2(A1.w), Dh[7], acc);
                acc = FDOT2(bc_h2(A2.x), Dh[8], acc);
                acc = FDOT2(bc_h2(A2.y), Dh[9], acc);
                const float dot = T_N - acc - SL;
                const float aN = (float)hN[lab];
                const float dN = (float)hN[20 + lab];
                const float lN = __log2f(aN) - dN;
                const float klL = fmaf(aN, dN - dlab, lN - llab);
                const float aN2 = (float)hN[nlab];
                const float dN2 = (float)hN[20 + nlab];
                const float lN2 = __log2f(aN2) - dN2;
                const float aOo = (float)hM[nlab];
                const float dOo = (float)hM[20 + nlab];
                const float lOo = __log2f(aOo) - dOo;
                const float klN = fmaf(aN2, dN2 - dOo, lN2 - lOo);
                const bool df = (lab != nlab);
                const float wg = df ? 1.0f : 0.0f;
                ek_k = wg * (fmaxf(K2F - klL, 0.0f) + fmaxf(K2F - klN, 0.0f));
                nk_k = dot - wg * (klL + klN);
                pc = df ? 2u : 0u;
            }
            const float vf = rvalid ? 1.0f : 0.0f;
            es_o = fmaf(vf, ek_k, es_o);
            ns_o = fmaf(vf, nk_k, ns_o);
            cnt += rvalid ? ((pc << 16) | (NC - pc)) : 0u;
        }
    }

    {
        const float2 swl = swen[lab <= NC - 1 ? lab : 0];
        e_s  = fmaf(es_o, swl.x, es_w);
        ne_s = fmaf(ns_o, swl.y, ns_w);
    }

    // ---- block reduction (scratch aliases dead patch[]) ----
#pragma unroll
    for (int off = 32; off > 0; off >>= 1) {
        e_s  += __shfl_down(e_s, off, 64);
        ne_s += __shfl_down(ne_s, off, 64);
        cnt  += __shfl_down(cnt, off, 64);
    }
    float* r_es = patch;                       // patch dead after stage 1;
    float* r_ns = patch + 8;                   // barrier already crossed
    unsigned int* r_cnt = reinterpret_cast<unsigned int*>(patch + 16);
    const int wid = tid >> 6, lane = tid & 63;
    if (lane == 0) { r_es[wid] = e_s; r_ns[wid] = ne_s; r_cnt[wid] = cnt; }
    __syncthreads();
    if (tid == 0) {
        float tes = 0.0f, tns = 0.0f;
        unsigned int tec = 0, tnc = 0;
#pragma unroll
        for (int w = 0; w < 8; ++w) {
            tes += r_es[w]; tns += r_ns[w];
            tec += r_cnt[w] >> 16; tnc += r_cnt[w] & 0xFFFFu;
        }
        const int bid = (blockIdx.z * gridDim.y + blockIdx.y) * gridDim.x + blockIdx.x;
        pb[bid].es = tes; pb[bid].ns = tns; pb[bid].ec = tec; pb[bid].nc = tnc;
    }
}

// ---------------- final reduce (1 block) ----------------
__global__ __launch_bounds__(256) void k_final(const Part* __restrict__ pb,
                                               float* __restrict__ out) {
    const int tid = threadIdx.x;
    double es = 0.0, ns = 0.0;
    long long ec = 0, nc = 0;
    for (int i = tid; i < NBLK; i += 256) {
        es += (double)pb[i].es; ns += (double)pb[i].ns;
        ec += (long long)pb[i].ec; nc += (long long)pb[i].nc;
    }
#pragma unroll
    for (int off = 32; off > 0; off >>= 1) {
        es += __shfl_down(es, off, 64);
        ns += __shfl_down(ns, off, 64);
        ec += __shfl_down(ec, off, 64);
        nc += __shfl_down(nc, off, 64);
    }
    __shared__ double ses[4], sns[4];
    __shared__ long long sec[4], snc[4];
    const int wid = tid >> 6, lane = tid & 63;
    if (lane == 0) { ses[wid] = es; sns[wid] = ns; sec[wid] = ec; snc[wid] = nc; }
    __syncthreads();
    if (tid == 0) {
        double tes = 0.0, tns = 0.0;
        long long tec = 0, tnc = 0;
#pragma unroll
        for (int w = 0; w < 4; ++w) { tes += ses[w]; tns += sns[w]; tec += sec[w]; tnc += snc[w]; }
        double ecd = (double)tec; if (ecd < 1.0) ecd = 1.0;
        double ncd = (double)tnc; if (ncd < 1.0) ncd = 1.0;
        out[0] = (float)((tes / ecd) * 0.01 + (tns / ncd) * 0.01);
    }
}

extern "C" void kernel_launch(void* const* d_in, const int* in_sizes, int n_in,
                              void* d_out, int out_size, void* d_ws, size_t ws_size,
                              hipStream_t stream) {
    const float* preds      = (const float*)d_in[0];  // (2,19,64,64) fp32
    const int*   targets    = (const int*)d_in[1];    // (2,512,512) int32
    const float* w_edge     = (const float*)d_in[2];  // (1,1,1,19,1,3) fp32
    const float* w_not_edge = (const float*)d_in[3];

    Part* pb = (Part*)d_ws;   // 1024 * 16 B; every slot written by k_fused

    dim3 grid(WW / TSX, HH / TSY, NB);   // 32 x 16 x 2 = 1024 blocks
    k_fused<<<grid, 512, 0, stream>>>(preds, targets, w_edge, w_not_edge, pb);
    k_final<<<1, 256, 0, stream>>>(pb, (float*)d_out);
}

// Round 10
// 99.416 us; speedup vs baseline: 1.1450x; 1.1450x over previous
//
#include <hip/hip_runtime.h>
#include <stdint.h>

// AAF loss, round 22: exact R16 kernel (best verified: 86.6 us total) with
// the final reduction FUSED via last-block pattern; k_final launch removed.
// Re-pairing lineage (R17-R19, R21) permanently abandoned: 4 consecutive
// spill regressions (VGPR 40-48, WRITE_SIZE 9-37 MB) vs this stable anchor.
// Fusion: each block writes Part -> __threadfence -> atomicAdd(counter);
// counter is zeroed per-iteration by a 4-byte hipMemsetAsync on the stream
// (graph-capture safe). The block observing prev==NBLK-1 re-reads all Parts
// (deterministic strided order + fixed shuffle tree, double accum -- same
// numerics class as the old k_final) and writes out[0].
// Core kernel byte-identical to R16: 32x16 tiles, 512 thr, 3 blocks/CU,
// log2-domain softmax (patch pre-scaled by log2e, raw v_exp/v_log, margin
// 3/ln2, ln2 folded into swe/swn), packed (a2,t2) f16 rows stride-20,
// fully-static stage-2 with in-loop cndmask capture of kl@lab / kl@nlab,
// uint8 TG, per-wave packed counts unpacked cross-wave.

#define NC 19
#define HH 512
#define WW 512
#define NB 2
#define TSY 32
#define TSX 16
#define HS 18                          // halo grid cols = TSX + 2
#define VS 34                          // halo grid rows = TSY + 2
#define HP (VS * HS)                   // 612
#define ATRS 20                        // row stride words: 80 B, 16B-aligned
#define PS 35                          // 7x5 source patch per class
#define NBLK 1024                      // 32 x 16 x 2 blocks
#define LOG2E 1.4426950408889634f
#define LN2 0.6931471805599453f
#define LOG2EPS -13.287712379549449f   // log2(1e-4)
#define K2F 4.3280851226668906f        // 3/ln2: KLD margin in log2 units
#define K2PAD 4.328125f                // (_Float16)K2F exactly (pad-slot value)

typedef _Float16 f16x2 __attribute__((ext_vector_type(2)));

#if __has_builtin(__builtin_amdgcn_exp2f)
#define EXP2F(x) __builtin_amdgcn_exp2f(x)
#else
#define EXP2F(x) __expf((x) * LN2)
#endif

#if __has_builtin(__builtin_amdgcn_fdot2)
#define FDOT2(a, b, c) __builtin_amdgcn_fdot2((a), (b), (c), false)
#else
#define FDOT2(a, b, c) fmaf((float)(a)[1], (float)(b)[1], fmaf((float)(a)[0], (float)(b)[0], (c)))
#endif

struct Part { float es, ns; unsigned int ec, nc; };

union U32F2 { uint32_t u; f16x2 h; };
__device__ __forceinline__ uint32_t bc_u32(f16x2 v) { U32F2 x; x.h = v; return x.u; }
__device__ __forceinline__ f16x2 bc_h2(uint32_t v) { U32F2 x; x.u = v; return x.h; }
__device__ __forceinline__ float extf(f16x2 v, int h) { return h ? (float)v[1] : (float)v[0]; }

// One pixel's softmax -> packed (a2,t2) row, written as 5 x b128
// (word 4i+0: a-pair 2i, 4i+1: t-pair 2i, 4i+2: a-pair 2i+1, 4i+3: t-pair 2i+1).
// d,l,t are in LOG2 units. KEEP: (d2,l2) pairs kept in registers.
// Returns label (255 = OOB pad).
template <bool KEEP>
__device__ __forceinline__ int pix_compute(const float* __restrict__ patch,
                                           const int* __restrict__ tg,
                                           int y, int x, int y0b, int x0b,
                                           uint32_t* __restrict__ ATrow,
                                           f16x2* Dh, f16x2* Lh) {
    const bool oob = ((unsigned)y >= (unsigned)HH) | ((unsigned)x >= (unsigned)WW);
    if (oob) {
        const _Float16 aP = (_Float16)1e-4f, dP = (_Float16)LOG2EPS;
        const _Float16 tP = (_Float16)((float)aP * (float)dP);
        const uint32_t aPP = bc_u32((f16x2){aP, aP});
        const uint32_t tPP = bc_u32((f16x2){tP, tP});
        const uint32_t aPL = bc_u32((f16x2){aP, (_Float16)0.0f});
        const uint32_t tPL = bc_u32((f16x2){tP, (_Float16)0.0f});
#pragma unroll
        for (int i = 0; i < 5; ++i) {
            uint4 wv;
            wv.x = aPP; wv.y = tPP;
            wv.z = (i < 4) ? aPP : aPL;
            wv.w = (i < 4) ? tPP : tPL;
            *reinterpret_cast<uint4*>(ATrow + 4 * i) = wv;
            if (KEEP) {
                Dh[2 * i] = (f16x2){dP, dP};
                Dh[2 * i + 1] = (i < 4) ? (f16x2){dP, dP} : (f16x2){dP, (_Float16)0.0f};
                Lh[2 * i] = (f16x2){(_Float16)0.0f, (_Float16)0.0f};
                Lh[2 * i + 1] = (f16x2){(_Float16)0.0f, (_Float16)0.0f};
            }
        }
        return 255;
    }

    const int lab = tg[(y << 9) + x];
    const float fy = (float)(y * 63) / 511.0f;
    const float fx = (float)(x * 63) / 511.0f;
    const int y0 = (int)fy, x0 = (int)fx;
    const float wy = fy - (float)y0, wx = fx - (float)x0;
    const int y1 = min(y0 + 1, 63), x1 = min(x0 + 1, 63);
    const float omwy = 1.0f - wy, omwx = 1.0f - wx;
    const float w00 = omwy * omwx, w01 = omwy * wx;
    const float w10 = wy * omwx,   w11 = wy * wx;
    const int o00 = (y0 - y0b) * 5 + (x0 - x0b);
    const int o01 = o00 + (x1 - x0);
    const int o10 = o00 + (y1 - y0) * 5;
    const int o11 = o10 + (x1 - x0);

    // v2 = logits * log2e (patch pre-scaled); no max-subtraction needed.
    float v2[NC], w[NC];
    float s = 0.0f;
#pragma unroll
    for (int c = 0; c < NC; ++c) {
        const float* pc_ = &patch[c * PS];
        const float vv = fmaf(pc_[o00], w00, fmaf(pc_[o01], w01,
                          fmaf(pc_[o10], w10, pc_[o11] * w11)));
        v2[c] = vv;
        const float e = EXP2F(vv);
        w[c] = e;
        s += e;
    }
    const float inv = 1.0f / s;
    const float lns2 = __log2f(s);            // log2 p = v2 - lns2

#pragma unroll
    for (int i = 0; i < 5; ++i) {
        _Float16 av[4], tv[4], dv[4], lv[4];
#pragma unroll
        for (int q = 0; q < 4; ++q) {
            const int c = 4 * i + q;
            _Float16 a16 = (_Float16)0.0f, d16 = (_Float16)0.0f,
                     l16 = (_Float16)0.0f, t16 = (_Float16)0.0f;
            if (c < NC) {
                const float p = w[c] * inv;
                const float la = fmaxf(v2[c] - lns2, LOG2EPS);   // log2(clip p)
                const float aa = fmaxf(p, 1e-4f);
                const float lb = __log2f(fmaxf(1.0f - p, 1e-4f));
                a16 = (_Float16)aa;
                d16 = (_Float16)(la - lb);
                l16 = (_Float16)lb;
                t16 = a16 * d16 + l16;        // v_fma_f16 (contracted)
            }
            av[q] = a16; tv[q] = t16; dv[q] = d16; lv[q] = l16;
        }
        uint4 wv;
        wv.x = bc_u32((f16x2){av[0], av[1]});
        wv.y = bc_u32((f16x2){tv[0], tv[1]});
        wv.z = bc_u32((f16x2){av[2], av[3]});
        wv.w = bc_u32((f16x2){tv[2], tv[3]});
        *reinterpret_cast<uint4*>(ATrow + 4 * i) = wv;   // ds_write_b128
        if (KEEP) {
            Dh[2 * i] = (f16x2){dv[0], dv[1]};
            Dh[2 * i + 1] = (f16x2){dv[2], dv[3]};
            Lh[2 * i] = (f16x2){lv[0], lv[1]};
            Lh[2 * i + 1] = (f16x2){lv[2], lv[3]};
        }
    }
    return lab;
}

__global__ __launch_bounds__(512, 6) void k_fused(const float* __restrict__ preds,
                                                  const int* __restrict__ targets,
                                                  const float* __restrict__ w_edge,
                                                  const float* __restrict__ w_not_edge,
                                                  Part* __restrict__ pb,
                                                  unsigned int* __restrict__ done_cnt,
                                                  float* __restrict__ out) {
    __shared__ __align__(16) uint32_t AT[HP * ATRS];  // 48,960 B
    __shared__ uint8_t TG[HP];                        // 612 B
    __shared__ float swe[NC], swn[NC];
    __shared__ float patch[NC * PS];                  // 2,660 B
    __shared__ float r_es[8], r_ns[8];
    __shared__ unsigned int r_cnt[8];
    __shared__ int last_flag;

    const int tid = threadIdx.x;
    const int bx = blockIdx.x, by = blockIdx.y, n = blockIdx.z;

    if (tid < NC) {
        {
            float a = w_edge[tid * 3 + 0], b = w_edge[tid * 3 + 1], c = w_edge[tid * 3 + 2];
            float m = fmaxf(a, fmaxf(b, c));
            float ea = __expf(a - m), eb = __expf(b - m), ec = __expf(c - m);
            swe[tid] = (ea / (ea + eb + ec)) * LN2;   // ln2: log2-domain rescale
        }
        {
            float a = w_not_edge[tid * 3 + 0], b = w_not_edge[tid * 3 + 1], c = w_not_edge[tid * 3 + 2];
            float m = fmaxf(a, fmaxf(b, c));
            float ea = __expf(a - m), eb = __expf(b - m), ec = __expf(c - m);
            swn[tid] = (ea / (ea + eb + ec)) * LN2;
        }
    }

    const int* tg = targets + (n << 18);
    const float* pbase = preds + (size_t)n * NC * 4096;

    const int ty = tid >> 4, tx = tid & 15;           // ty 0..31
    const int hi = (ty + 1) * HS + (tx + 1);
    const int DOFF[8] = {-HS - 1, -HS, -HS + 1, -1, 1, HS - 1, HS, HS + 1};
    const f16x2 one2 = {(_Float16)1.0f, (_Float16)1.0f};
    const f16x2 k32 = {(_Float16)K2F, (_Float16)K2F};
    const f16x2 z2 = {(_Float16)0.0f, (_Float16)0.0f};

    float e_s = 0.0f, ne_s = 0.0f;
    unsigned int cnt = 0;               // e_c << 16 | ne_c (per-thread max 16|152)

    // ---- stage 0: stage 7x5x19 source patch, pre-scaled by log2e ----
    const int yT = max(by * TSY - 1, 0), xL = max(bx * TSX - 1, 0);
    const int y0b = (yT * 63) / 511, x0b = (xL * 63) / 511;
    for (int t = tid; t < NC * PS; t += 512) {
        const int c = t / PS, r = t - c * PS;
        const int ry = r / 5, rx = r - ry * 5;
        const int sy = min(y0b + ry, 63), sx = min(x0b + rx, 63);
        patch[t] = pbase[c * 4096 + (sy << 6) + sx] * LOG2E;
    }
    __syncthreads();

    // ---- stage 1: halo ring first (temps die), then own pixel ----
    if (tid < 100) {
        int i;
        if (tid < 18)      i = tid;                       // top row (row 0)
        else if (tid < 36) i = 33 * HS + (tid - 18);      // bottom row (row 33)
        else if (tid < 68) i = (tid - 35) * HS;           // left col (rows 1..32)
        else               i = (tid - 67) * HS + 17;      // right col (rows 1..32)
        const int hy = i / HS, hx = i - hy * HS;
        TG[i] = (uint8_t)pix_compute<false>(patch, tg, by * TSY + hy - 1, bx * TSX + hx - 1,
                                            y0b, x0b, &AT[i * ATRS], nullptr, nullptr);
    }

    f16x2 Dh[10], Lh[10];
    const int lab = pix_compute<true>(patch, tg, by * TSY + ty, bx * TSX + tx,
                                      y0b, x0b, &AT[hi * ATRS], Dh, Lh);
    TG[hi] = (uint8_t)lab;
    __syncthreads();

    // ---- stage 2 (all kl values in log2 units; margin = K2F) ----
    const bool interior_blk = (bx > 0) & (bx < 31) & (by > 0) & (by < 15);
    const int plab = lab >> 1, hlab = lab & 1;
    float es_h = 0.0f, ns_h = 0.0f;
    unsigned int cnt_h = 0;

    if (interior_blk) {
#pragma unroll
        for (int k = 0; k < 8; ++k) {
            const int np = hi + DOFF[k];
            const int nlab = (int)TG[np];
            const int pn = nlab >> 1, hn = nlab & 1;
            const uint32_t* wbp = &AT[np * ATRS];
            float dot0 = 0.0f, dot1 = 0.0f;
            f16x2 klLw = z2, klNw = z2;
#pragma unroll
            for (int i = 0; i < 5; ++i) {
                const uint4 rd = *reinterpret_cast<const uint4*>(wbp + 4 * i);  // b128
                const int j0 = 2 * i, j1 = 2 * i + 1;
                const f16x2 kl20 = bc_h2(rd.y) - (bc_h2(rd.x) * Dh[j0] + Lh[j0]);
                const f16x2 kl21 = bc_h2(rd.w) - (bc_h2(rd.z) * Dh[j1] + Lh[j1]);
                dot0 = FDOT2(kl20, one2, dot0);
                dot1 = FDOT2(kl21, one2, dot1);
                klLw = (j0 == plab) ? kl20 : klLw;
                klLw = (j1 == plab) ? kl21 : klLw;
                klNw = (j0 == pn) ? kl20 : klNw;
                klNw = (j1 == pn) ? kl21 : klNw;
            }
            const float dot = dot0 + dot1;
            const float klL = extf(klLw, hlab);
            const float klN = extf(klNw, hn);
            const bool df = (lab != nlab);
            const float w = df ? 1.0f : 0.0f;
            es_h = fmaf(w, fmaxf(K2F - klL, 0.0f) + fmaxf(K2F - klN, 0.0f), es_h);
            ns_h += dot - w * (klL + klN);
            cnt_h += df ? ((2u << 16) | (NC - 2)) : NC;
        }
        e_s = fmaf(es_h, swe[lab], e_s);
        ne_s = fmaf(ns_h, swn[lab], ne_s);
        cnt += cnt_h;
    } else if (lab <= NC - 1) {
        // ---- border path: OOB-pad neighbors + reverse-ignore ----
#pragma unroll
        for (int k = 0; k < 8; ++k) {
            const int off = DOFF[k];
            const int rlab = (int)TG[hi - off];
            const int np = hi + off;
            const int nlab = (int)TG[np];
            const int pn = nlab >> 1, hn = nlab & 1;   // pad: pn=127, never hit
            const uint32_t* wbp = &AT[np * ATRS];
            float dot0 = 0.0f, dot1 = 0.0f, ekall = 0.0f;
            f16x2 klLw = z2, klNw = z2;
#pragma unroll
            for (int i = 0; i < 5; ++i) {
                const uint4 rd = *reinterpret_cast<const uint4*>(wbp + 4 * i);
                const int j0 = 2 * i, j1 = 2 * i + 1;
                const f16x2 kl20 = bc_h2(rd.y) - (bc_h2(rd.x) * Dh[j0] + Lh[j0]);
                const f16x2 kl21 = bc_h2(rd.w) - (bc_h2(rd.z) * Dh[j1] + Lh[j1]);
                dot0 = FDOT2(kl20, one2, dot0);
                dot1 = FDOT2(kl21, one2, dot1);
                f16x2 m0 = k32 - kl20, m1 = k32 - kl21;
                m0[0] = m0[0] > (_Float16)0.0f ? m0[0] : (_Float16)0.0f;
                m0[1] = m0[1] > (_Float16)0.0f ? m0[1] : (_Float16)0.0f;
                m1[0] = m1[0] > (_Float16)0.0f ? m1[0] : (_Float16)0.0f;
                m1[1] = m1[1] > (_Float16)0.0f ? m1[1] : (_Float16)0.0f;
                ekall = FDOT2(m0, one2, ekall);
                ekall = FDOT2(m1, one2, ekall);
                klLw = (j0 == plab) ? kl20 : klLw;
                klLw = (j1 == plab) ? kl21 : klLw;
                klNw = (j0 == pn) ? kl20 : klNw;
                klNw = (j1 == pn) ? kl21 : klNw;
            }
            const float dot = dot0 + dot1;
            const float klL = extf(klLw, hlab);
            const float klN = extf(klNw, hn);
            const bool isPad = (nlab == 255);
            const bool df = (lab != nlab) && !isPad;
            const float w = df ? 1.0f : 0.0f;
            const float ek_int = w * (fmaxf(K2F - klL, 0.0f) + fmaxf(K2F - klN, 0.0f));
            const float nk_int = dot - w * (klL + klN);
            const float ek_pad = ekall - K2PAD;      // drop pad-class slot (kl=0 -> K2)
            const float ek_k = isPad ? ek_pad : ek_int;
            const float nk_k = isPad ? 0.0f : nk_int;
            const unsigned int pc = isPad ? NC : (df ? 2u : 0u);
            const bool valid = (rlab <= NC - 1);
            const float vf = valid ? 1.0f : 0.0f;
            es_h = fmaf(vf, ek_k, es_h);
            ns_h = fmaf(vf, nk_k, ns_h);
            cnt_h += valid ? ((pc << 16) | (NC - pc)) : 0u;
        }
        e_s = fmaf(es_h, swe[lab], e_s);
        ne_s = fmaf(ns_h, swn[lab], ne_s);
        cnt += cnt_h;
    }

    // ---- block reduction: packed 32-bit within wave, unpacked cross-wave ----
#pragma unroll
    for (int off = 32; off > 0; off >>= 1) {
        e_s  += __shfl_down(e_s, off, 64);
        ne_s += __shfl_down(ne_s, off, 64);
        cnt  += __shfl_down(cnt, off, 64);
    }
    const int wid = tid >> 6, lane = tid & 63;
    if (lane == 0) { r_es[wid] = e_s; r_ns[wid] = ne_s; r_cnt[wid] = cnt; }
    __syncthreads();
    if (tid == 0) {
        float tes = 0.0f, tns = 0.0f;
        unsigned int tec = 0, tnc = 0;
#pragma unroll
        for (int w = 0; w < 8; ++w) {
            tes += r_es[w]; tns += r_ns[w];
            tec += r_cnt[w] >> 16; tnc += r_cnt[w] & 0xFFFFu;
        }
        const int bid = (blockIdx.z * gridDim.y + blockIdx.y) * gridDim.x + blockIdx.x;
        pb[bid].es = tes; pb[bid].ns = tns; pb[bid].ec = tec; pb[bid].nc = tnc;
        __threadfence();                       // Part visible device-wide
        const unsigned int prev = atomicAdd(done_cnt, 1u);
        last_flag = (prev == NBLK - 1) ? 1 : 0;
    }
    __syncthreads();

    // ---- last block: fused final reduction (replaces k_final launch) ----
    if (last_flag) {
        __threadfence();                       // acquire all Parts
        double es = 0.0, ns = 0.0;
        long long ec = 0, nc = 0;
        for (int i = tid; i < NBLK; i += 512) {
            es += (double)pb[i].es; ns += (double)pb[i].ns;
            ec += (long long)pb[i].ec; nc += (long long)pb[i].nc;
        }
#pragma unroll
        for (int off = 32; off > 0; off >>= 1) {
            es += __shfl_down(es, off, 64);
            ns += __shfl_down(ns, off, 64);
            ec += __shfl_down(ec, off, 64);
            nc += __shfl_down(nc, off, 64);
        }
        // cross-wave via LDS (reuse patch; all prior readers are done)
        double* ses = reinterpret_cast<double*>(patch);
        double* sns = ses + 8;
        long long* sec = reinterpret_cast<long long*>(sns + 8);
        long long* snc = sec + 8;
        if (lane == 0) { ses[wid] = es; sns[wid] = ns; sec[wid] = ec; snc[wid] = nc; }
        __syncthreads();
        if (tid == 0) {
            double tes = 0.0, tns = 0.0;
            long long tec = 0, tnc = 0;
#pragma unroll
            for (int w = 0; w < 8; ++w) { tes += ses[w]; tns += sns[w]; tec += sec[w]; tnc += snc[w]; }
            double ecd = (double)tec; if (ecd < 1.0) ecd = 1.0;
            double ncd = (double)tnc; if (ncd < 1.0) ncd = 1.0;
            out[0] = (float)((tes / ecd) * 0.01 + (tns / ncd) * 0.01);
        }
    }
}

extern "C" void kernel_launch(void* const* d_in, const int* in_sizes, int n_in,
                              void* d_out, int out_size, void* d_ws, size_t ws_size,
                              hipStream_t stream) {
    const float* preds      = (const float*)d_in[0];  // (2,19,64,64) fp32
    const int*   targets    = (const int*)d_in[1];    // (2,512,512) int32
    const float* w_edge     = (const float*)d_in[2];  // (1,1,1,19,1,3) fp32
    const float* w_not_edge = (const float*)d_in[3];

    Part* pb = (Part*)d_ws;                                   // 1024 * 16 B
    unsigned int* done_cnt = (unsigned int*)((char*)d_ws + NBLK * sizeof(Part));

    // Zero the completion counter each iteration (workspace is re-poisoned by
    // the harness between iterations). Stream-ordered -> graph-capture safe.
    hipMemsetAsync(done_cnt, 0, sizeof(unsigned int), stream);

    dim3 grid(WW / TSX, HH / TSY, NB);   // 32 x 16 x 2 = 1024 blocks
    k_fused<<<grid, 512, 0, stream>>>(preds, targets, w_edge, w_not_edge,
                                      pb, done_cnt, (float*)d_out);
}

// Round 11
// 85.990 us; speedup vs baseline: 1.3238x; 1.1561x over previous
//
#include <hip/hip_runtime.h>
#include <stdint.h>

// AAF loss, round 23: EXACT revert to R16 -- the measured session best
// (86.6 us total; k_fused ~28.6 us by calibrated budget model).
// Device code is byte-identical to the R16 submission.
// Post-R16 experiment ledger (all reverted):
//  - R17/R18/R19/R21 re-pairing lineage: 4x spill/low-VGPR regressions
//    (VGPR 40-48, WRITE_SIZE 9-37 MB, k_fused 40-88 us). Abandoned.
//  - R20 halo-SIMD rotation: neutral (88.2 vs 86.6, within noise).
//  - R22 fused final reduction: regressed k_fused itself 28.6->43.8 us
//    (VGPR 40 rematerialization + threadfence L2-writeback serialization);
//    two-kernel structure restored.
// Structure: 32x16 tiles, 512 threads, 3 blocks/CU (launch_bounds(512,6));
// log2-domain softmax (patch pre-scaled by log2e, raw v_exp/v_log, margin
// 3/ln2, ln2 folded into swe/swn); packed (a2,t2) f16 rows stride-20;
// fully-static stage-2 with in-loop cndmask capture of kl@lab / kl@nlab;
// uint8 TG; per-wave packed counts, unpacked cross-wave; separate k_final.

#define NC 19
#define HH 512
#define WW 512
#define NB 2
#define TSY 32
#define TSX 16
#define HS 18                          // halo grid cols = TSX + 2
#define VS 34                          // halo grid rows = TSY + 2
#define HP (VS * HS)                   // 612
#define ATRS 20                        // row stride words: 80 B, 16B-aligned
#define PS 35                          // 7x5 source patch per class
#define NBLK 1024                      // 32 x 16 x 2 blocks
#define LOG2E 1.4426950408889634f
#define LN2 0.6931471805599453f
#define LOG2EPS -13.287712379549449f   // log2(1e-4)
#define K2F 4.3280851226668906f        // 3/ln2: KLD margin in log2 units
#define K2PAD 4.328125f                // (_Float16)K2F exactly (pad-slot value)

typedef _Float16 f16x2 __attribute__((ext_vector_type(2)));

#if __has_builtin(__builtin_amdgcn_exp2f)
#define EXP2F(x) __builtin_amdgcn_exp2f(x)
#else
#define EXP2F(x) __expf((x) * LN2)
#endif

#if __has_builtin(__builtin_amdgcn_fdot2)
#define FDOT2(a, b, c) __builtin_amdgcn_fdot2((a), (b), (c), false)
#else
#define FDOT2(a, b, c) fmaf((float)(a)[1], (float)(b)[1], fmaf((float)(a)[0], (float)(b)[0], (c)))
#endif

struct Part { float es, ns; unsigned int ec, nc; };

union U32F2 { uint32_t u; f16x2 h; };
__device__ __forceinline__ uint32_t bc_u32(f16x2 v) { U32F2 x; x.h = v; return x.u; }
__device__ __forceinline__ f16x2 bc_h2(uint32_t v) { U32F2 x; x.u = v; return x.h; }
__device__ __forceinline__ float extf(f16x2 v, int h) { return h ? (float)v[1] : (float)v[0]; }

// One pixel's softmax -> packed (a2,t2) row, written as 5 x b128
// (word 4i+0: a-pair 2i, 4i+1: t-pair 2i, 4i+2: a-pair 2i+1, 4i+3: t-pair 2i+1).
// d,l,t are in LOG2 units. KEEP: (d2,l2) pairs kept in registers.
// Returns label (255 = OOB pad).
template <bool KEEP>
__device__ __forceinline__ int pix_compute(const float* __restrict__ patch,
                                           const int* __restrict__ tg,
                                           int y, int x, int y0b, int x0b,
                                           uint32_t* __restrict__ ATrow,
                                           f16x2* Dh, f16x2* Lh) {
    const bool oob = ((unsigned)y >= (unsigned)HH) | ((unsigned)x >= (unsigned)WW);
    if (oob) {
        const _Float16 aP = (_Float16)1e-4f, dP = (_Float16)LOG2EPS;
        const _Float16 tP = (_Float16)((float)aP * (float)dP);
        const uint32_t aPP = bc_u32((f16x2){aP, aP});
        const uint32_t tPP = bc_u32((f16x2){tP, tP});
        const uint32_t aPL = bc_u32((f16x2){aP, (_Float16)0.0f});
        const uint32_t tPL = bc_u32((f16x2){tP, (_Float16)0.0f});
#pragma unroll
        for (int i = 0; i < 5; ++i) {
            uint4 wv;
            wv.x = aPP; wv.y = tPP;
            wv.z = (i < 4) ? aPP : aPL;
            wv.w = (i < 4) ? tPP : tPL;
            *reinterpret_cast<uint4*>(ATrow + 4 * i) = wv;
            if (KEEP) {
                Dh[2 * i] = (f16x2){dP, dP};
                Dh[2 * i + 1] = (i < 4) ? (f16x2){dP, dP} : (f16x2){dP, (_Float16)0.0f};
                Lh[2 * i] = (f16x2){(_Float16)0.0f, (_Float16)0.0f};
                Lh[2 * i + 1] = (f16x2){(_Float16)0.0f, (_Float16)0.0f};
            }
        }
        return 255;
    }

    const int lab = tg[(y << 9) + x];
    const float fy = (float)(y * 63) / 511.0f;
    const float fx = (float)(x * 63) / 511.0f;
    const int y0 = (int)fy, x0 = (int)fx;
    const float wy = fy - (float)y0, wx = fx - (float)x0;
    const int y1 = min(y0 + 1, 63), x1 = min(x0 + 1, 63);
    const float omwy = 1.0f - wy, omwx = 1.0f - wx;
    const float w00 = omwy * omwx, w01 = omwy * wx;
    const float w10 = wy * omwx,   w11 = wy * wx;
    const int o00 = (y0 - y0b) * 5 + (x0 - x0b);
    const int o01 = o00 + (x1 - x0);
    const int o10 = o00 + (y1 - y0) * 5;
    const int o11 = o10 + (x1 - x0);

    // v2 = logits * log2e (patch pre-scaled); no max-subtraction needed.
    float v2[NC], w[NC];
    float s = 0.0f;
#pragma unroll
    for (int c = 0; c < NC; ++c) {
        const float* pc_ = &patch[c * PS];
        const float vv = fmaf(pc_[o00], w00, fmaf(pc_[o01], w01,
                          fmaf(pc_[o10], w10, pc_[o11] * w11)));
        v2[c] = vv;
        const float e = EXP2F(vv);
        w[c] = e;
        s += e;
    }
    const float inv = 1.0f / s;
    const float lns2 = __log2f(s);            // log2 p = v2 - lns2

#pragma unroll
    for (int i = 0; i < 5; ++i) {
        _Float16 av[4], tv[4], dv[4], lv[4];
#pragma unroll
        for (int q = 0; q < 4; ++q) {
            const int c = 4 * i + q;
            _Float16 a16 = (_Float16)0.0f, d16 = (_Float16)0.0f,
                     l16 = (_Float16)0.0f, t16 = (_Float16)0.0f;
            if (c < NC) {
                const float p = w[c] * inv;
                const float la = fmaxf(v2[c] - lns2, LOG2EPS);   // log2(clip p)
                const float aa = fmaxf(p, 1e-4f);
                const float lb = __log2f(fmaxf(1.0f - p, 1e-4f));
                a16 = (_Float16)aa;
                d16 = (_Float16)(la - lb);
                l16 = (_Float16)lb;
                t16 = a16 * d16 + l16;        // v_fma_f16 (contracted)
            }
            av[q] = a16; tv[q] = t16; dv[q] = d16; lv[q] = l16;
        }
        uint4 wv;
        wv.x = bc_u32((f16x2){av[0], av[1]});
        wv.y = bc_u32((f16x2){tv[0], tv[1]});
        wv.z = bc_u32((f16x2){av[2], av[3]});
        wv.w = bc_u32((f16x2){tv[2], tv[3]});
        *reinterpret_cast<uint4*>(ATrow + 4 * i) = wv;   // ds_write_b128
        if (KEEP) {
            Dh[2 * i] = (f16x2){dv[0], dv[1]};
            Dh[2 * i + 1] = (f16x2){dv[2], dv[3]};
            Lh[2 * i] = (f16x2){lv[0], lv[1]};
            Lh[2 * i + 1] = (f16x2){lv[2], lv[3]};
        }
    }
    return lab;
}

__global__ __launch_bounds__(512, 6) void k_fused(const float* __restrict__ preds,
                                                  const int* __restrict__ targets,
                                                  const float* __restrict__ w_edge,
                                                  const float* __restrict__ w_not_edge,
                                                  Part* __restrict__ pb) {
    __shared__ __align__(16) uint32_t AT[HP * ATRS];  // 48,960 B
    __shared__ uint8_t TG[HP];                        // 612 B
    __shared__ float swe[NC], swn[NC];
    __shared__ float patch[NC * PS];                  // 2,660 B
    __shared__ float r_es[8], r_ns[8];
    __shared__ unsigned int r_cnt[8];

    const int tid = threadIdx.x;
    const int bx = blockIdx.x, by = blockIdx.y, n = blockIdx.z;

    if (tid < NC) {
        {
            float a = w_edge[tid * 3 + 0], b = w_edge[tid * 3 + 1], c = w_edge[tid * 3 + 2];
            float m = fmaxf(a, fmaxf(b, c));
            float ea = __expf(a - m), eb = __expf(b - m), ec = __expf(c - m);
            swe[tid] = (ea / (ea + eb + ec)) * LN2;   // ln2: log2-domain rescale
        }
        {
            float a = w_not_edge[tid * 3 + 0], b = w_not_edge[tid * 3 + 1], c = w_not_edge[tid * 3 + 2];
            float m = fmaxf(a, fmaxf(b, c));
            float ea = __expf(a - m), eb = __expf(b - m), ec = __expf(c - m);
            swn[tid] = (ea / (ea + eb + ec)) * LN2;
        }
    }

    const int* tg = targets + (n << 18);
    const float* pbase = preds + (size_t)n * NC * 4096;

    const int ty = tid >> 4, tx = tid & 15;           // ty 0..31
    const int hi = (ty + 1) * HS + (tx + 1);
    const int DOFF[8] = {-HS - 1, -HS, -HS + 1, -1, 1, HS - 1, HS, HS + 1};
    const f16x2 one2 = {(_Float16)1.0f, (_Float16)1.0f};
    const f16x2 k32 = {(_Float16)K2F, (_Float16)K2F};
    const f16x2 z2 = {(_Float16)0.0f, (_Float16)0.0f};

    float e_s = 0.0f, ne_s = 0.0f;
    unsigned int cnt = 0;               // e_c << 16 | ne_c (per-thread max 16|152)

    // ---- stage 0: stage 7x5x19 source patch, pre-scaled by log2e ----
    const int yT = max(by * TSY - 1, 0), xL = max(bx * TSX - 1, 0);
    const int y0b = (yT * 63) / 511, x0b = (xL * 63) / 511;
    for (int t = tid; t < NC * PS; t += 512) {
        const int c = t / PS, r = t - c * PS;
        const int ry = r / 5, rx = r - ry * 5;
        const int sy = min(y0b + ry, 63), sx = min(x0b + rx, 63);
        patch[t] = pbase[c * 4096 + (sy << 6) + sx] * LOG2E;
    }
    __syncthreads();

    // ---- stage 1: halo ring first (temps die), then own pixel ----
    if (tid < 100) {
        int i;
        if (tid < 18)      i = tid;                       // top row (row 0)
        else if (tid < 36) i = 33 * HS + (tid - 18);      // bottom row (row 33)
        else if (tid < 68) i = (tid - 35) * HS;           // left col (rows 1..32)
        else               i = (tid - 67) * HS + 17;      // right col (rows 1..32)
        const int hy = i / HS, hx = i - hy * HS;
        TG[i] = (uint8_t)pix_compute<false>(patch, tg, by * TSY + hy - 1, bx * TSX + hx - 1,
                                            y0b, x0b, &AT[i * ATRS], nullptr, nullptr);
    }

    f16x2 Dh[10], Lh[10];
    const int lab = pix_compute<true>(patch, tg, by * TSY + ty, bx * TSX + tx,
                                      y0b, x0b, &AT[hi * ATRS], Dh, Lh);
    TG[hi] = (uint8_t)lab;
    __syncthreads();

    // ---- stage 2 (all kl values in log2 units; margin = K2F) ----
    const bool interior_blk = (bx > 0) & (bx < 31) & (by > 0) & (by < 15);
    const int plab = lab >> 1, hlab = lab & 1;
    float es_h = 0.0f, ns_h = 0.0f;
    unsigned int cnt_h = 0;

    if (interior_blk) {
#pragma unroll
        for (int k = 0; k < 8; ++k) {
            const int np = hi + DOFF[k];
            const int nlab = (int)TG[np];
            const int pn = nlab >> 1, hn = nlab & 1;
            const uint32_t* wbp = &AT[np * ATRS];
            float dot0 = 0.0f, dot1 = 0.0f;
            f16x2 klLw = z2, klNw = z2;
#pragma unroll
            for (int i = 0; i < 5; ++i) {
                const uint4 rd = *reinterpret_cast<const uint4*>(wbp + 4 * i);  // b128
                const int j0 = 2 * i, j1 = 2 * i + 1;
                const f16x2 kl20 = bc_h2(rd.y) - (bc_h2(rd.x) * Dh[j0] + Lh[j0]);
                const f16x2 kl21 = bc_h2(rd.w) - (bc_h2(rd.z) * Dh[j1] + Lh[j1]);
                dot0 = FDOT2(kl20, one2, dot0);
                dot1 = FDOT2(kl21, one2, dot1);
                klLw = (j0 == plab) ? kl20 : klLw;
                klLw = (j1 == plab) ? kl21 : klLw;
                klNw = (j0 == pn) ? kl20 : klNw;
                klNw = (j1 == pn) ? kl21 : klNw;
            }
            const float dot = dot0 + dot1;
            const float klL = extf(klLw, hlab);
            const float klN = extf(klNw, hn);
            const bool df = (lab != nlab);
            const float w = df ? 1.0f : 0.0f;
            es_h = fmaf(w, fmaxf(K2F - klL, 0.0f) + fmaxf(K2F - klN, 0.0f), es_h);
            ns_h += dot - w * (klL + klN);
            cnt_h += df ? ((2u << 16) | (NC - 2)) : NC;
        }
        e_s = fmaf(es_h, swe[lab], e_s);
        ne_s = fmaf(ns_h, swn[lab], ne_s);
        cnt += cnt_h;
    } else if (lab <= NC - 1) {
        // ---- border path: OOB-pad neighbors + reverse-ignore ----
#pragma unroll
        for (int k = 0; k < 8; ++k) {
            const int off = DOFF[k];
            const int rlab = (int)TG[hi - off];
            const int np = hi + off;
            const int nlab = (int)TG[np];
            const int pn = nlab >> 1, hn = nlab & 1;   // pad: pn=127, never hit
            const uint32_t* wbp = &AT[np * ATRS];
            float dot0 = 0.0f, dot1 = 0.0f, ekall = 0.0f;
            f16x2 klLw = z2, klNw = z2;
#pragma unroll
            for (int i = 0; i < 5; ++i) {
                const uint4 rd = *reinterpret_cast<const uint4*>(wbp + 4 * i);
                const int j0 = 2 * i, j1 = 2 * i + 1;
                const f16x2 kl20 = bc_h2(rd.y) - (bc_h2(rd.x) * Dh[j0] + Lh[j0]);
                const f16x2 kl21 = bc_h2(rd.w) - (bc_h2(rd.z) * Dh[j1] + Lh[j1]);
                dot0 = FDOT2(kl20, one2, dot0);
                dot1 = FDOT2(kl21, one2, dot1);
                f16x2 m0 = k32 - kl20, m1 = k32 - kl21;
                m0[0] = m0[0] > (_Float16)0.0f ? m0[0] : (_Float16)0.0f;
                m0[1] = m0[1] > (_Float16)0.0f ? m0[1] : (_Float16)0.0f;
                m1[0] = m1[0] > (_Float16)0.0f ? m1[0] : (_Float16)0.0f;
                m1[1] = m1[1] > (_Float16)0.0f ? m1[1] : (_Float16)0.0f;
                ekall = FDOT2(m0, one2, ekall);
                ekall = FDOT2(m1, one2, ekall);
                klLw = (j0 == plab) ? kl20 : klLw;
                klLw = (j1 == plab) ? kl21 : klLw;
                klNw = (j0 == pn) ? kl20 : klNw;
                klNw = (j1 == pn) ? kl21 : klNw;
            }
            const float dot = dot0 + dot1;
            const float klL = extf(klLw, hlab);
            const float klN = extf(klNw, hn);
            const bool isPad = (nlab == 255);
            const bool df = (lab != nlab) && !isPad;
            const float w = df ? 1.0f : 0.0f;
            const float ek_int = w * (fmaxf(K2F - klL, 0.0f) + fmaxf(K2F - klN, 0.0f));
            const float nk_int = dot - w * (klL + klN);
            const float ek_pad = ekall - K2PAD;      // drop pad-class slot (kl=0 -> K2)
            const float ek_k = isPad ? ek_pad : ek_int;
            const float nk_k = isPad ? 0.0f : nk_int;
            const unsigned int pc = isPad ? NC : (df ? 2u : 0u);
            const bool valid = (rlab <= NC - 1);
            const float vf = valid ? 1.0f : 0.0f;
            es_h = fmaf(vf, ek_k, es_h);
            ns_h = fmaf(vf, nk_k, ns_h);
            cnt_h += valid ? ((pc << 16) | (NC - pc)) : 0u;
        }
        e_s = fmaf(es_h, swe[lab], e_s);
        ne_s = fmaf(ns_h, swn[lab], ne_s);
        cnt += cnt_h;
    }

    // ---- block reduction: packed 32-bit within wave (max 1024<<16|9728),
    //      unpacked across the 8 waves ----
#pragma unroll
    for (int off = 32; off > 0; off >>= 1) {
        e_s  += __shfl_down(e_s, off, 64);
        ne_s += __shfl_down(ne_s, off, 64);
        cnt  += __shfl_down(cnt, off, 64);
    }
    const int wid = tid >> 6, lane = tid & 63;
    if (lane == 0) { r_es[wid] = e_s; r_ns[wid] = ne_s; r_cnt[wid] = cnt; }
    __syncthreads();
    if (tid == 0) {
        float tes = 0.0f, tns = 0.0f;
        unsigned int tec = 0, tnc = 0;
#pragma unroll
        for (int w = 0; w < 8; ++w) {
            tes += r_es[w]; tns += r_ns[w];
            tec += r_cnt[w] >> 16; tnc += r_cnt[w] & 0xFFFFu;
        }
        const int bid = (blockIdx.z * gridDim.y + blockIdx.y) * gridDim.x + blockIdx.x;
        pb[bid].es = tes; pb[bid].ns = tns; pb[bid].ec = tec; pb[bid].nc = tnc;
    }
}

// ---------------- final reduce (1 block) ----------------
__global__ __launch_bounds__(256) void k_final(const Part* __restrict__ pb,
                                               float* __restrict__ out) {
    const int tid = threadIdx.x;
    double es = 0.0, ns = 0.0;
    long long ec = 0, nc = 0;
    for (int i = tid; i < NBLK; i += 256) {
        es += (double)pb[i].es; ns += (double)pb[i].ns;
        ec += (long long)pb[i].ec; nc += (long long)pb[i].nc;
    }
#pragma unroll
    for (int off = 32; off > 0; off >>= 1) {
        es += __shfl_down(es, off, 64);
        ns += __shfl_down(ns, off, 64);
        ec += __shfl_down(ec, off, 64);
        nc += __shfl_down(nc, off, 64);
    }
    __shared__ double ses[4], sns[4];
    __shared__ long long sec[4], snc[4];
    const int wid = tid >> 6, lane = tid & 63;
    if (lane == 0) { ses[wid] = es; sns[wid] = ns; sec[wid] = ec; snc[wid] = nc; }
    __syncthreads();
    if (tid == 0) {
        double tes = 0.0, tns = 0.0;
        long long tec = 0, tnc = 0;
#pragma unroll
        for (int w = 0; w < 4; ++w) { tes += ses[w]; tns += sns[w]; tec += sec[w]; tnc += snc[w]; }
        double ecd = (double)tec; if (ecd < 1.0) ecd = 1.0;
        double ncd = (double)tnc; if (ncd < 1.0) ncd = 1.0;
        out[0] = (float)((tes / ecd) * 0.01 + (tns / ncd) * 0.01);
    }
}

extern "C" void kernel_launch(void* const* d_in, const int* in_sizes, int n_in,
                              void* d_out, int out_size, void* d_ws, size_t ws_size,
                              hipStream_t stream) {
    const float* preds      = (const float*)d_in[0];  // (2,19,64,64) fp32
    const int*   targets    = (const int*)d_in[1];    // (2,512,512) int32
    const float* w_edge     = (const float*)d_in[2];  // (1,1,1,19,1,3) fp32
    const float* w_not_edge = (const float*)d_in[3];

    Part* pb = (Part*)d_ws;   // 1024 * 16 B; every slot written by k_fused

    dim3 grid(WW / TSX, HH / TSY, NB);   // 32 x 16 x 2 = 1024 blocks
    k_fused<<<grid, 512, 0, stream>>>(preds, targets, w_edge, w_not_edge, pb);
    k_final<<<1, 256, 0, stream>>>(pb, (float*)d_out);
}